// Round 7
// baseline (546.878 us; speedup 1.0000x reference)
//
#include <hip/hip_runtime.h>

typedef unsigned short u16;
typedef float f32x4 __attribute__((ext_vector_type(4)));
typedef short bf16x8 __attribute__((ext_vector_type(8)));
typedef u16 u16x4 __attribute__((ext_vector_type(4)));
typedef unsigned int uint2v __attribute__((ext_vector_type(2)));
typedef unsigned int uint4v __attribute__((ext_vector_type(4)));

// B=2, C=64, D=3, N=4096, K=16, E=128, H=256

static __device__ __forceinline__ u16 f2bf(float x) {
    union { float f; unsigned int u; } v; v.f = x;
    unsigned int u = v.u;
    unsigned int r = u + 0x7fffu + ((u >> 16) & 1u);   // RNE
    return (u16)(r >> 16);
}

static __device__ __forceinline__ float bf2f(u16 h) {
    union { unsigned int u; float f; } v; v.u = ((unsigned int)h) << 16;
    return v.f;
}

// packed RNE f32x2 -> bf16x2
static __device__ __forceinline__ unsigned int pk2(float a, float b) {
    return (unsigned int)f2bf(a) | ((unsigned int)f2bf(b) << 16);
}

// ---------------- mean over D (+ absorbed weight prep on blocks 0..255) ----
__global__ __launch_bounds__(256) void mean_kernel(const float* __restrict__ x,
                                                   float* __restrict__ pc,
                                                   const float* __restrict__ W1,
                                                   const float* __restrict__ W2,
                                                   const float* __restrict__ W3,
                                                   u16* __restrict__ W2bf,
                                                   u16* __restrict__ W3bf,
                                                   float* __restrict__ W1dT,
                                                   float* __restrict__ W1bT) {
    int t = blockIdx.x * 256 + threadIdx.x;            // over B*C*N = 524288
    int n = t & 4095;
    int bc = t >> 12;
    const float* xp = x + bc * 3 * 4096 + n;
    pc[t] = (xp[0] + xp[4096] + xp[8192]) / 3.0f;

    if (t < 65536) {                                   // prep (blocks 0..255)
        W2bf[t] = f2bf(W2[t]);
        if (t < 16384) {
            W3bf[t] = f2bf(W3[t]);
            int c = t >> 8, h = t & 255;
            float wa = W1[h * 128 + c];
            float wb = W1[h * 128 + 64 + c];
            W1dT[t] = wa - wb;                         // [c][h]
            W1bT[t] = wb;                              // [c][h]
        }
    }
}

// ---------------- per-point squared norm ----------------
__global__ __launch_bounds__(256) void sq_kernel(const float* __restrict__ pc,
                                                 float* __restrict__ sq) {
    int t = blockIdx.x * 256 + threadIdx.x;            // over B*N = 8192
    int b = t >> 12, n = t & 4095;
    float s = 0.f;
    #pragma unroll
    for (int c = 0; c < 64; ++c) {
        float v = pc[(b * 64 + c) * 4096 + n];
        s += v * v;
    }
    sq[t] = s;
}

// Branch-free sorted insert: exact fp32 compare, ~5 VALU/step, no divergence.
#define INSERT(dist, idxv) do { \
    float _v = (dist); int _vi = (idxv); \
    _Pragma("unroll") \
    for (int _s = 0; _s < 16; ++_s) { \
        bool _c = _v < bd[_s]; \
        float _nb = _c ? _v : bd[_s]; \
        float _nv = _c ? bd[_s] : _v; \
        int _nbi = _c ? _vi : bi[_s]; \
        int _nvi = _c ? bi[_s] : _vi; \
        bd[_s] = _nb; _v = _nv; bi[_s] = _nbi; _vi = _nvi; \
    } } while (0)

// ---------------- KNN phase 1: per-chunk top-16 ----------------
__global__ __launch_bounds__(256, 3) void knn_part_kernel(const float* __restrict__ pc,
                                                          const float* __restrict__ sq,
                                                          float* __restrict__ pd,
                                                          int* __restrict__ pi) {
    __shared__ float ptile[64][128];
    __shared__ float sqt[128];
    int tid = threadIdx.x;
    int bid = blockIdx.x;
    int ch = bid & 31, qb = (bid >> 5) & 15, b = bid >> 9;
    int n = qb * 256 + tid;
    int m0 = ch * 128;

    #pragma unroll
    for (int it = 0; it < 8; ++it) {
        int lin4 = it * 256 + tid;                     // 2048 float4s
        int c = lin4 >> 5, mm4 = (lin4 & 31) * 4;
        *(float4*)&ptile[c][mm4] =
            *(const float4*)&pc[(b * 64 + c) * 4096 + m0 + mm4];
    }
    if (tid < 128) sqt[tid] = sq[b * 4096 + m0 + tid];

    float qv[64];
    #pragma unroll
    for (int c = 0; c < 64; ++c) qv[c] = pc[(b * 64 + c) * 4096 + n];
    float sqn = sq[b * 4096 + n];

    float bd[16]; int bi[16];
    #pragma unroll
    for (int s = 0; s < 16; ++s) { bd[s] = 3.4e38f; bi[s] = -1; }
    __syncthreads();

    for (int mb = 0; mb < 128; mb += 4) {
        float d0 = 0.f, d1 = 0.f, d2 = 0.f, d3 = 0.f;
        #pragma unroll
        for (int c = 0; c < 64; ++c) {
            float4 pv = *(const float4*)&ptile[c][mb];
            float qc = qv[c];
            d0 = fmaf(qc, pv.x, d0);
            d1 = fmaf(qc, pv.y, d1);
            d2 = fmaf(qc, pv.z, d2);
            d3 = fmaf(qc, pv.w, d3);
        }
        int m = m0 + mb;
        float e0 = (sqn - 2.f * d0) + sqt[mb + 0]; if (m + 0 == n) e0 = 3.4e38f;
        float e1 = (sqn - 2.f * d1) + sqt[mb + 1]; if (m + 1 == n) e1 = 3.4e38f;
        float e2 = (sqn - 2.f * d2) + sqt[mb + 2]; if (m + 2 == n) e2 = 3.4e38f;
        float e3 = (sqn - 2.f * d3) + sqt[mb + 3]; if (m + 3 == n) e3 = 3.4e38f;
        INSERT(e0, m + 0);
        INSERT(e1, m + 1);
        INSERT(e2, m + 2);
        INSERT(e3, m + 3);
    }
    int base = ((b * 4096 + n) * 32 + ch) * 16;
    #pragma unroll
    for (int s = 0; s < 16; ++s) { pd[base + s] = bd[s]; pi[base + s] = bi[s]; }
}

// ---------------- KNN phase 2: wave-per-query extract-min x16 ----------------
__global__ __launch_bounds__(256) void knn_merge_kernel(const float* __restrict__ pd,
                                                        const int* __restrict__ pi,
                                                        int* __restrict__ idxw) {
    int tid = threadIdx.x;
    int lane = tid & 63;
    int q = blockIdx.x * 4 + (tid >> 6);               // 2048 blocks, 4 queries each
    int base = q * 512;

    float d[8]; int ix[8];
    #pragma unroll
    for (int j = 0; j < 8; ++j) {
        d[j] = pd[base + lane + 64 * j];
        ix[j] = pi[base + lane + 64 * j];
    }

    for (int e = 0; e < 16; ++e) {
        float lmd = d[0]; int lmi = ix[0];
        #pragma unroll
        for (int j = 1; j < 8; ++j) {
            bool c = d[j] < lmd;
            lmd = c ? d[j] : lmd;
            lmi = c ? ix[j] : lmi;
        }
        float wm = lmd;
        #pragma unroll
        for (int off = 32; off; off >>= 1)
            wm = fminf(wm, __shfl_xor(wm, off));
        unsigned long long msk = __ballot(lmd == wm);
        int L = (int)__ffsll(msk) - 1;
        int wmi = __shfl(lmi, L);
        if (lane == 0) idxw[q * 16 + e] = wmi;
        if (lane == L) {
            #pragma unroll
            for (int j = 0; j < 8; ++j)
                if (ix[j] == wmi) d[j] = 3.4e38f;
        }
    }
}

// ---------------- Qbf[b][m][h] = bf16(W1b @ mean_pc), 8 cols/block ----------
__global__ __launch_bounds__(256) void q_kernel(const float* __restrict__ pc,
                                               const float* __restrict__ W1bT,
                                               u16* __restrict__ Qbf) {
    int h = threadIdx.x;
    int bid = blockIdx.x;                              // 1024
    int b = bid >> 9, m0 = (bid & 511) * 8;
    float a0 = 0.f, a1 = 0.f, a2 = 0.f, a3 = 0.f;
    float a4 = 0.f, a5 = 0.f, a6 = 0.f, a7 = 0.f;
    for (int c = 0; c < 64; ++c) {
        float w = W1bT[c * 256 + h];
        const float* pr = pc + (b * 64 + c) * 4096 + m0;
        float4 p0 = *(const float4*)pr;
        float4 p1 = *(const float4*)(pr + 4);
        a0 = fmaf(w, p0.x, a0); a1 = fmaf(w, p0.y, a1);
        a2 = fmaf(w, p0.z, a2); a3 = fmaf(w, p0.w, a3);
        a4 = fmaf(w, p1.x, a4); a5 = fmaf(w, p1.y, a5);
        a6 = fmaf(w, p1.z, a6); a7 = fmaf(w, p1.w, a7);
    }
    int ob = (b * 4096 + m0) * 256 + h;
    Qbf[ob] = f2bf(a0); Qbf[ob + 256] = f2bf(a1);
    Qbf[ob + 512] = f2bf(a2); Qbf[ob + 768] = f2bf(a3);
    Qbf[ob + 1024] = f2bf(a4); Qbf[ob + 1280] = f2bf(a5);
    Qbf[ob + 1536] = f2bf(a6); Qbf[ob + 1792] = f2bf(a7);
}

// ---------------- Pbf[b][d][n][h] = bf16((W1a-W1b) @ x + b1), 8 cols/block ---
__global__ __launch_bounds__(256) void p_kernel(const float* __restrict__ x,
                                               const float* __restrict__ W1dT,
                                               const float* __restrict__ b1,
                                               u16* __restrict__ Pbf) {
    int h = threadIdx.x;
    int bid = blockIdx.x;                              // 3072
    int b = bid / 1536;
    int rem = bid % 1536;
    int d = rem >> 9;
    int n0 = (rem & 511) * 8;
    float bias = b1[h];
    float a0 = bias, a1 = bias, a2 = bias, a3 = bias;
    float a4 = bias, a5 = bias, a6 = bias, a7 = bias;
    for (int c = 0; c < 64; ++c) {
        float w = W1dT[c * 256 + h];
        const float* xr = x + ((b * 64 + c) * 3 + d) * 4096 + n0;
        float4 x0 = *(const float4*)xr;
        float4 x1 = *(const float4*)(xr + 4);
        a0 = fmaf(w, x0.x, a0); a1 = fmaf(w, x0.y, a1);
        a2 = fmaf(w, x0.z, a2); a3 = fmaf(w, x0.w, a3);
        a4 = fmaf(w, x1.x, a4); a5 = fmaf(w, x1.y, a5);
        a6 = fmaf(w, x1.z, a6); a7 = fmaf(w, x1.w, a7);
    }
    int ob = ((b * 3 + d) * 4096 + n0) * 256 + h;
    Pbf[ob] = f2bf(a0); Pbf[ob + 256] = f2bf(a1);
    Pbf[ob + 512] = f2bf(a2); Pbf[ob + 768] = f2bf(a3);
    Pbf[ob + 1024] = f2bf(a4); Pbf[ob + 1280] = f2bf(a5);
    Pbf[ob + 1536] = f2bf(a6); Pbf[ob + 1792] = f2bf(a7);
}

// ---------------- fused layer2+layer3+maxK+residual (bf16 MFMA) ----------------
// 2 points per block processed SEQUENTIALLY: hL = 48x264 (25.3 KB) -> 4+ blocks
// per CU (launch_bounds(256,4); VGPR <= 128). h1 build uses 32-lane rows with
// b128 LDS writes (all banks hit). Writes for n, n+1 merge in L2 (same block).
__global__ __launch_bounds__(256, 4) void fused_mlp_kernel(const float* __restrict__ x,
                                                           const u16* __restrict__ Pbf,
                                                           const u16* __restrict__ Qbf,
                                                           const int* __restrict__ idxw,
                                                           const u16* __restrict__ W2bf,
                                                           const u16* __restrict__ W3bf,
                                                           const float* __restrict__ b2,
                                                           const float* __restrict__ b3,
                                                           float* __restrict__ out) {
    __shared__ u16 hL[48][264];                        // stride 264: 16B-aligned rows

    int tid = threadIdx.x;
    int bid = blockIdx.x;                              // 4096
    int b = bid >> 11;
    int n0 = (bid & 2047) * 2;

    int w = tid >> 6, lane = tid & 63;
    int cl = lane & 15, q = lane >> 4;
    int r = lane >> 5, l32 = lane & 31;

    const u16* Arow = W2bf + (w * 64 + cl) * 256 + q * 8;
    const u16* A3row = W3bf + (w * 16 + cl) * 256 + q * 8;

    #pragma unroll 1
    for (int pp = 0; pp < 2; ++pp) {
        int n = n0 + pp;

        // ---- build h1 = relu(P + Q) into LDS (bf16) ----
        // wave w covers k = w*4..w*4+3 in 2 (pair x r) steps; lane reads 16 B.
        {
            float pf[3][8];
            #pragma unroll
            for (int d = 0; d < 3; ++d) {
                bf16x8 pv8 = *(const bf16x8*)&Pbf[((b * 3 + d) * 4096 + n) * 256 + l32 * 8];
                #pragma unroll
                for (int j = 0; j < 8; ++j) pf[d][j] = bf2f((u16)pv8[j]);
            }
            const int* idq = idxw + (b * 4096 + n) * 16;
            #pragma unroll
            for (int pr = 0; pr < 2; ++pr) {
                int kk = (w << 2) + (pr << 1) + r;
                int m = idq[kk];
                bf16x8 qv8 = *(const bf16x8*)&Qbf[(b * 4096 + m) * 256 + l32 * 8];
                float qf[8];
                #pragma unroll
                for (int j = 0; j < 8; ++j) qf[j] = bf2f((u16)qv8[j]);
                #pragma unroll
                for (int d = 0; d < 3; ++d) {
                    uint4v hv;
                    hv[0] = pk2(fmaxf(pf[d][0] + qf[0], 0.f), fmaxf(pf[d][1] + qf[1], 0.f));
                    hv[1] = pk2(fmaxf(pf[d][2] + qf[2], 0.f), fmaxf(pf[d][3] + qf[3], 0.f));
                    hv[2] = pk2(fmaxf(pf[d][4] + qf[4], 0.f), fmaxf(pf[d][5] + qf[5], 0.f));
                    hv[3] = pk2(fmaxf(pf[d][6] + qf[6], 0.f), fmaxf(pf[d][7] + qf[7], 0.f));
                    *(uint4v*)&hL[d * 16 + kk][l32 * 8] = hv;
                }
            }
        }
        __syncthreads();

        // ---- layer 2: h2 = relu(W2 @ h1 + b2), 256 rows x 48 cols ----
        f32x4 acc[4][3];
        #pragma unroll
        for (int i = 0; i < 4; ++i)
            #pragma unroll
            for (int jt = 0; jt < 3; ++jt)
                acc[i][jt] = (f32x4){0.f, 0.f, 0.f, 0.f};

        for (int kt = 0; kt < 8; ++kt) {
            int k0 = kt * 32;
            bf16x8 a[4], bb[3];
            #pragma unroll
            for (int i = 0; i < 4; ++i)
                a[i] = *(const bf16x8*)(Arow + i * 4096 + k0);
            #pragma unroll
            for (int jt = 0; jt < 3; ++jt)
                bb[jt] = *(const bf16x8*)(&hL[jt * 16 + cl][k0 + q * 8]);
            #pragma unroll
            for (int i = 0; i < 4; ++i)
                #pragma unroll
                for (int jt = 0; jt < 3; ++jt)
                    acc[i][jt] = __builtin_amdgcn_mfma_f32_16x16x32_bf16(a[i], bb[jt], acc[i][jt], 0, 0, 0);
        }
        __syncthreads();   // everyone done reading h1

        // write h2 (bf16) into the same LDS buffer; bias from L1
        #pragma unroll
        for (int i = 0; i < 4; ++i) {
            int rowb = w * 64 + i * 16 + q * 4;
            float4 bv = *(const float4*)(b2 + rowb);
            #pragma unroll
            for (int jt = 0; jt < 3; ++jt) {
                f32x4 v = acc[i][jt];
                uint2v hv;
                hv[0] = pk2(fmaxf(v[0] + bv.x, 0.f), fmaxf(v[1] + bv.y, 0.f));
                hv[1] = pk2(fmaxf(v[2] + bv.z, 0.f), fmaxf(v[3] + bv.w, 0.f));
                *(uint2v*)&hL[jt * 16 + cl][rowb] = hv;
            }
        }
        __syncthreads();

        // ---- layer 3: r = W3 @ h2 + b3, 64 rows x 48 cols ----
        f32x4 acc3[3];
        #pragma unroll
        for (int jt = 0; jt < 3; ++jt) acc3[jt] = (f32x4){0.f, 0.f, 0.f, 0.f};

        for (int kt = 0; kt < 8; ++kt) {
            int k0 = kt * 32;
            bf16x8 a3 = *(const bf16x8*)(A3row + k0);
            #pragma unroll
            for (int jt = 0; jt < 3; ++jt) {
                bf16x8 bb = *(const bf16x8*)(&hL[jt * 16 + cl][k0 + q * 8]);
                acc3[jt] = __builtin_amdgcn_mfma_f32_16x16x32_bf16(a3, bb, acc3[jt], 0, 0, 0);
            }
        }

        // ---- epilogue: +b3, max over k (16 cols = cl), +x, store ----
        int rowb = w * 16 + q * 4;
        float4 b3v = *(const float4*)(b3 + rowb);
        #pragma unroll
        for (int jt = 0; jt < 3; ++jt) {
            int d = jt;
            f32x4 v = acc3[jt];
            v[0] += b3v.x;
            v[1] += b3v.y;
            v[2] += b3v.z;
            v[3] += b3v.w;
            #pragma unroll
            for (int off = 1; off < 16; off <<= 1) {
                v[0] = fmaxf(v[0], __shfl_xor(v[0], off));
                v[1] = fmaxf(v[1], __shfl_xor(v[1], off));
                v[2] = fmaxf(v[2], __shfl_xor(v[2], off));
                v[3] = fmaxf(v[3], __shfl_xor(v[3], off));
            }
            if (cl == 0) {
                #pragma unroll
                for (int rr = 0; rr < 4; ++rr) {
                    int addr = ((b * 64 + rowb + rr) * 3 + d) * 4096 + n;
                    out[addr] = v[rr] + x[addr];
                }
            }
        }
        __syncthreads();   // protect hL before next pass overwrites it
    }
}

extern "C" void kernel_launch(void* const* d_in, const int* in_sizes, int n_in,
                              void* d_out, int out_size, void* d_ws, size_t ws_size,
                              hipStream_t stream) {
    (void)in_sizes; (void)n_in; (void)out_size; (void)ws_size;
    const float* x  = (const float*)d_in[0];
    const float* W1 = (const float*)d_in[1];
    const float* b1 = (const float*)d_in[2];
    const float* W2 = (const float*)d_in[3];
    const float* b2 = (const float*)d_in[4];
    const float* W3 = (const float*)d_in[5];
    const float* b3 = (const float*)d_in[6];
    float* out = (float*)d_out;

    char* ws = (char*)d_ws;
    float* pc   = (float*)(ws + 0);          // 2,097,152 B  (B,C,N)
    float* sq   = (float*)(ws + 2097152);    //    32,768 B  (B,N)
    int*   idxw = (int*)  (ws + 2129920);    //   524,288 B  (B,N,K)
    u16*   Qbf  = (u16*)  (ws + 2654208);    // 4,194,304 B  (B,N,H) bf16
    u16*   Pbf  = (u16*)  (ws + 6848512);    // 12,582,912 B (B,D,N,H) bf16
    u16*   W2bf = (u16*)  (ws + 19431424);   //   131,072 B
    u16*   W3bf = (u16*)  (ws + 19562496);   //    32,768 B
    float* W1dT = (float*)(ws + 19595264);   //    65,536 B
    float* W1bT = (float*)(ws + 19660800);   //    65,536 B
    // KNN partials (16,777,216 B each). pd aliases the not-yet-written Qbf+Pbf
    // region exactly; pi lives after the weight buffers. q/p kernels run after
    // knn_merge, so the aliasing is safe. (prep runs first, inside mean_kernel,
    // and its buffers at 19.43-19.73 MB don't overlap pd or pi.)
    float* pd   = (float*)(ws + 2654208);    // ends 19,431,424
    int*   pi   = (int*)  (ws + 19726336);   // ends 36,503,552

    mean_kernel<<<2048, 256, 0, stream>>>(x, pc, W1, W2, W3, W2bf, W3bf, W1dT, W1bT);
    sq_kernel<<<32, 256, 0, stream>>>(pc, sq);
    knn_part_kernel<<<1024, 256, 0, stream>>>(pc, sq, pd, pi);
    knn_merge_kernel<<<2048, 256, 0, stream>>>(pd, pi, idxw);
    q_kernel<<<1024, 256, 0, stream>>>(pc, W1bT, Qbf);
    p_kernel<<<3072, 256, 0, stream>>>(x, W1dT, b1, Pbf);
    fused_mlp_kernel<<<4096, 256, 0, stream>>>(x, Pbf, Qbf, idxw, W2bf, W3bf, b2, b3, out);
}

// Round 8
// 467.041 us; speedup vs baseline: 1.1709x; 1.1709x over previous
//
#include <hip/hip_runtime.h>

typedef unsigned short u16;
typedef float f32x4 __attribute__((ext_vector_type(4)));
typedef short bf16x8 __attribute__((ext_vector_type(8)));
typedef u16 u16x4 __attribute__((ext_vector_type(4)));
typedef unsigned int uint2v __attribute__((ext_vector_type(2)));
typedef unsigned int uint4v __attribute__((ext_vector_type(4)));

// B=2, C=64, D=3, N=4096, K=16, E=128, H=256

static __device__ __forceinline__ u16 f2bf(float x) {
    union { float f; unsigned int u; } v; v.f = x;
    unsigned int u = v.u;
    unsigned int r = u + 0x7fffu + ((u >> 16) & 1u);   // RNE
    return (u16)(r >> 16);
}

static __device__ __forceinline__ float bf2f(u16 h) {
    union { unsigned int u; float f; } v; v.u = ((unsigned int)h) << 16;
    return v.f;
}

// packed RNE f32x2 -> bf16x2
static __device__ __forceinline__ unsigned int pk2(float a, float b) {
    return (unsigned int)f2bf(a) | ((unsigned int)f2bf(b) << 16);
}

// ---------------- mean over D (+ absorbed weight prep on blocks 0..255) ----
__global__ __launch_bounds__(256) void mean_kernel(const float* __restrict__ x,
                                                   float* __restrict__ pc,
                                                   const float* __restrict__ W1,
                                                   const float* __restrict__ W2,
                                                   const float* __restrict__ W3,
                                                   u16* __restrict__ W2bf,
                                                   u16* __restrict__ W3bf,
                                                   float* __restrict__ W1dT,
                                                   float* __restrict__ W1bT) {
    int t = blockIdx.x * 256 + threadIdx.x;            // over B*C*N = 524288
    int n = t & 4095;
    int bc = t >> 12;
    const float* xp = x + bc * 3 * 4096 + n;
    pc[t] = (xp[0] + xp[4096] + xp[8192]) / 3.0f;

    if (t < 65536) {                                   // prep (blocks 0..255)
        W2bf[t] = f2bf(W2[t]);
        if (t < 16384) {
            W3bf[t] = f2bf(W3[t]);
            int c = t >> 8, h = t & 255;
            float wa = W1[h * 128 + c];
            float wb = W1[h * 128 + 64 + c];
            W1dT[t] = wa - wb;                         // [c][h]
            W1bT[t] = wb;                              // [c][h]
        }
    }
}

// ---------------- per-point squared norm ----------------
__global__ __launch_bounds__(256) void sq_kernel(const float* __restrict__ pc,
                                                 float* __restrict__ sq) {
    int t = blockIdx.x * 256 + threadIdx.x;            // over B*N = 8192
    int b = t >> 12, n = t & 4095;
    float s = 0.f;
    #pragma unroll
    for (int c = 0; c < 64; ++c) {
        float v = pc[(b * 64 + c) * 4096 + n];
        s += v * v;
    }
    sq[t] = s;
}

// Branch-free sorted insert: exact fp32 compare, ~5 VALU/step, no divergence.
#define INSERT(dist, idxv) do { \
    float _v = (dist); int _vi = (idxv); \
    _Pragma("unroll") \
    for (int _s = 0; _s < 16; ++_s) { \
        bool _c = _v < bd[_s]; \
        float _nb = _c ? _v : bd[_s]; \
        float _nv = _c ? bd[_s] : _v; \
        int _nbi = _c ? _vi : bi[_s]; \
        int _nvi = _c ? bi[_s] : _vi; \
        bd[_s] = _nb; _v = _nv; bi[_s] = _nbi; _vi = _nvi; \
    } } while (0)

// ---------------- KNN phase 1: per-chunk top-16 ----------------
__global__ __launch_bounds__(256, 3) void knn_part_kernel(const float* __restrict__ pc,
                                                          const float* __restrict__ sq,
                                                          float* __restrict__ pd,
                                                          int* __restrict__ pi) {
    __shared__ float ptile[64][128];
    __shared__ float sqt[128];
    int tid = threadIdx.x;
    int bid = blockIdx.x;
    int ch = bid & 31, qb = (bid >> 5) & 15, b = bid >> 9;
    int n = qb * 256 + tid;
    int m0 = ch * 128;

    #pragma unroll
    for (int it = 0; it < 8; ++it) {
        int lin4 = it * 256 + tid;                     // 2048 float4s
        int c = lin4 >> 5, mm4 = (lin4 & 31) * 4;
        *(float4*)&ptile[c][mm4] =
            *(const float4*)&pc[(b * 64 + c) * 4096 + m0 + mm4];
    }
    if (tid < 128) sqt[tid] = sq[b * 4096 + m0 + tid];

    float qv[64];
    #pragma unroll
    for (int c = 0; c < 64; ++c) qv[c] = pc[(b * 64 + c) * 4096 + n];
    float sqn = sq[b * 4096 + n];

    float bd[16]; int bi[16];
    #pragma unroll
    for (int s = 0; s < 16; ++s) { bd[s] = 3.4e38f; bi[s] = -1; }
    __syncthreads();

    for (int mb = 0; mb < 128; mb += 4) {
        float d0 = 0.f, d1 = 0.f, d2 = 0.f, d3 = 0.f;
        #pragma unroll
        for (int c = 0; c < 64; ++c) {
            float4 pv = *(const float4*)&ptile[c][mb];
            float qc = qv[c];
            d0 = fmaf(qc, pv.x, d0);
            d1 = fmaf(qc, pv.y, d1);
            d2 = fmaf(qc, pv.z, d2);
            d3 = fmaf(qc, pv.w, d3);
        }
        int m = m0 + mb;
        float e0 = (sqn - 2.f * d0) + sqt[mb + 0]; if (m + 0 == n) e0 = 3.4e38f;
        float e1 = (sqn - 2.f * d1) + sqt[mb + 1]; if (m + 1 == n) e1 = 3.4e38f;
        float e2 = (sqn - 2.f * d2) + sqt[mb + 2]; if (m + 2 == n) e2 = 3.4e38f;
        float e3 = (sqn - 2.f * d3) + sqt[mb + 3]; if (m + 3 == n) e3 = 3.4e38f;
        INSERT(e0, m + 0);
        INSERT(e1, m + 1);
        INSERT(e2, m + 2);
        INSERT(e3, m + 3);
    }
    int base = ((b * 4096 + n) * 32 + ch) * 16;
    #pragma unroll
    for (int s = 0; s < 16; ++s) { pd[base + s] = bd[s]; pi[base + s] = bi[s]; }
}

// ---------------- KNN phase 2: wave-per-query extract-min x16 ----------------
__global__ __launch_bounds__(256) void knn_merge_kernel(const float* __restrict__ pd,
                                                        const int* __restrict__ pi,
                                                        int* __restrict__ idxw) {
    int tid = threadIdx.x;
    int lane = tid & 63;
    int q = blockIdx.x * 4 + (tid >> 6);               // 2048 blocks, 4 queries each
    int base = q * 512;

    float d[8]; int ix[8];
    #pragma unroll
    for (int j = 0; j < 8; ++j) {
        d[j] = pd[base + lane + 64 * j];
        ix[j] = pi[base + lane + 64 * j];
    }

    for (int e = 0; e < 16; ++e) {
        float lmd = d[0]; int lmi = ix[0];
        #pragma unroll
        for (int j = 1; j < 8; ++j) {
            bool c = d[j] < lmd;
            lmd = c ? d[j] : lmd;
            lmi = c ? ix[j] : lmi;
        }
        float wm = lmd;
        #pragma unroll
        for (int off = 32; off; off >>= 1)
            wm = fminf(wm, __shfl_xor(wm, off));
        unsigned long long msk = __ballot(lmd == wm);
        int L = (int)__ffsll(msk) - 1;
        int wmi = __shfl(lmi, L);
        if (lane == 0) idxw[q * 16 + e] = wmi;
        if (lane == L) {
            #pragma unroll
            for (int j = 0; j < 8; ++j)
                if (ix[j] == wmi) d[j] = 3.4e38f;
        }
    }
}

// ---------------- Qbf[b][m][h] = bf16(W1b @ mean_pc), 8 cols/block ----------
__global__ __launch_bounds__(256) void q_kernel(const float* __restrict__ pc,
                                               const float* __restrict__ W1bT,
                                               u16* __restrict__ Qbf) {
    int h = threadIdx.x;
    int bid = blockIdx.x;                              // 1024
    int b = bid >> 9, m0 = (bid & 511) * 8;
    float a0 = 0.f, a1 = 0.f, a2 = 0.f, a3 = 0.f;
    float a4 = 0.f, a5 = 0.f, a6 = 0.f, a7 = 0.f;
    for (int c = 0; c < 64; ++c) {
        float w = W1bT[c * 256 + h];
        const float* pr = pc + (b * 64 + c) * 4096 + m0;
        float4 p0 = *(const float4*)pr;
        float4 p1 = *(const float4*)(pr + 4);
        a0 = fmaf(w, p0.x, a0); a1 = fmaf(w, p0.y, a1);
        a2 = fmaf(w, p0.z, a2); a3 = fmaf(w, p0.w, a3);
        a4 = fmaf(w, p1.x, a4); a5 = fmaf(w, p1.y, a5);
        a6 = fmaf(w, p1.z, a6); a7 = fmaf(w, p1.w, a7);
    }
    int ob = (b * 4096 + m0) * 256 + h;
    Qbf[ob] = f2bf(a0); Qbf[ob + 256] = f2bf(a1);
    Qbf[ob + 512] = f2bf(a2); Qbf[ob + 768] = f2bf(a3);
    Qbf[ob + 1024] = f2bf(a4); Qbf[ob + 1280] = f2bf(a5);
    Qbf[ob + 1536] = f2bf(a6); Qbf[ob + 1792] = f2bf(a7);
}

// ---------------- Pbf[b][d][n][h] = bf16((W1a-W1b) @ x + b1), 8 cols/block ---
__global__ __launch_bounds__(256) void p_kernel(const float* __restrict__ x,
                                               const float* __restrict__ W1dT,
                                               const float* __restrict__ b1,
                                               u16* __restrict__ Pbf) {
    int h = threadIdx.x;
    int bid = blockIdx.x;                              // 3072
    int b = bid / 1536;
    int rem = bid % 1536;
    int d = rem >> 9;
    int n0 = (rem & 511) * 8;
    float bias = b1[h];
    float a0 = bias, a1 = bias, a2 = bias, a3 = bias;
    float a4 = bias, a5 = bias, a6 = bias, a7 = bias;
    for (int c = 0; c < 64; ++c) {
        float w = W1dT[c * 256 + h];
        const float* xr = x + ((b * 64 + c) * 3 + d) * 4096 + n0;
        float4 x0 = *(const float4*)xr;
        float4 x1 = *(const float4*)(xr + 4);
        a0 = fmaf(w, x0.x, a0); a1 = fmaf(w, x0.y, a1);
        a2 = fmaf(w, x0.z, a2); a3 = fmaf(w, x0.w, a3);
        a4 = fmaf(w, x1.x, a4); a5 = fmaf(w, x1.y, a5);
        a6 = fmaf(w, x1.z, a6); a7 = fmaf(w, x1.w, a7);
    }
    int ob = ((b * 3 + d) * 4096 + n0) * 256 + h;
    Pbf[ob] = f2bf(a0); Pbf[ob + 256] = f2bf(a1);
    Pbf[ob + 512] = f2bf(a2); Pbf[ob + 768] = f2bf(a3);
    Pbf[ob + 1024] = f2bf(a4); Pbf[ob + 1280] = f2bf(a5);
    Pbf[ob + 1536] = f2bf(a6); Pbf[ob + 1792] = f2bf(a7);
}

// ---------------- fused layer2+layer3+maxK+residual (bf16 MFMA) ----------------
// 2 points per block processed SEQUENTIALLY: hL = 48x264 (25.3 KB). Plain
// launch_bounds(256): compiler free to use ~104 VGPR (NO min-waves clamp —
// R7's (256,4) forced VGPR=64 and spilled 1.3 GB to scratch). Expected
// occupancy: min(LDS 6, VGPR 4) = 4 blocks/CU.
__global__ __launch_bounds__(256) void fused_mlp_kernel(const float* __restrict__ x,
                                                        const u16* __restrict__ Pbf,
                                                        const u16* __restrict__ Qbf,
                                                        const int* __restrict__ idxw,
                                                        const u16* __restrict__ W2bf,
                                                        const u16* __restrict__ W3bf,
                                                        const float* __restrict__ b2,
                                                        const float* __restrict__ b3,
                                                        float* __restrict__ out) {
    __shared__ u16 hL[48][264];                        // stride 264: 16B-aligned rows

    int tid = threadIdx.x;
    int bid = blockIdx.x;                              // 4096
    int b = bid >> 11;
    int n0 = (bid & 2047) * 2;

    int w = tid >> 6, lane = tid & 63;
    int cl = lane & 15, q = lane >> 4;
    int r = lane >> 5, l32 = lane & 31;

    const u16* Arow = W2bf + (w * 64 + cl) * 256 + q * 8;
    const u16* A3row = W3bf + (w * 16 + cl) * 256 + q * 8;

    #pragma unroll 1
    for (int pp = 0; pp < 2; ++pp) {
        int n = n0 + pp;

        // ---- build h1 = relu(P + Q) into LDS (bf16) ----
        // wave w covers k = w*4..w*4+3 in 2 (pair x r) steps; lane reads 16 B.
        {
            float pf[3][8];
            #pragma unroll
            for (int d = 0; d < 3; ++d) {
                bf16x8 pv8 = *(const bf16x8*)&Pbf[((b * 3 + d) * 4096 + n) * 256 + l32 * 8];
                #pragma unroll
                for (int j = 0; j < 8; ++j) pf[d][j] = bf2f((u16)pv8[j]);
            }
            const int* idq = idxw + (b * 4096 + n) * 16;
            #pragma unroll
            for (int pr = 0; pr < 2; ++pr) {
                int kk = (w << 2) + (pr << 1) + r;
                int m = idq[kk];
                bf16x8 qv8 = *(const bf16x8*)&Qbf[(b * 4096 + m) * 256 + l32 * 8];
                float qf[8];
                #pragma unroll
                for (int j = 0; j < 8; ++j) qf[j] = bf2f((u16)qv8[j]);
                #pragma unroll
                for (int d = 0; d < 3; ++d) {
                    uint4v hv;
                    hv[0] = pk2(fmaxf(pf[d][0] + qf[0], 0.f), fmaxf(pf[d][1] + qf[1], 0.f));
                    hv[1] = pk2(fmaxf(pf[d][2] + qf[2], 0.f), fmaxf(pf[d][3] + qf[3], 0.f));
                    hv[2] = pk2(fmaxf(pf[d][4] + qf[4], 0.f), fmaxf(pf[d][5] + qf[5], 0.f));
                    hv[3] = pk2(fmaxf(pf[d][6] + qf[6], 0.f), fmaxf(pf[d][7] + qf[7], 0.f));
                    *(uint4v*)&hL[d * 16 + kk][l32 * 8] = hv;
                }
            }
        }
        __syncthreads();

        // ---- layer 2: h2 = relu(W2 @ h1 + b2), 256 rows x 48 cols ----
        f32x4 acc[4][3];
        #pragma unroll
        for (int i = 0; i < 4; ++i)
            #pragma unroll
            for (int jt = 0; jt < 3; ++jt)
                acc[i][jt] = (f32x4){0.f, 0.f, 0.f, 0.f};

        for (int kt = 0; kt < 8; ++kt) {
            int k0 = kt * 32;
            bf16x8 a[4], bb[3];
            #pragma unroll
            for (int i = 0; i < 4; ++i)
                a[i] = *(const bf16x8*)(Arow + i * 4096 + k0);
            #pragma unroll
            for (int jt = 0; jt < 3; ++jt)
                bb[jt] = *(const bf16x8*)(&hL[jt * 16 + cl][k0 + q * 8]);
            #pragma unroll
            for (int i = 0; i < 4; ++i)
                #pragma unroll
                for (int jt = 0; jt < 3; ++jt)
                    acc[i][jt] = __builtin_amdgcn_mfma_f32_16x16x32_bf16(a[i], bb[jt], acc[i][jt], 0, 0, 0);
        }
        __syncthreads();   // everyone done reading h1

        // write h2 (bf16) into the same LDS buffer; bias from L1
        #pragma unroll
        for (int i = 0; i < 4; ++i) {
            int rowb = w * 64 + i * 16 + q * 4;
            float4 bv = *(const float4*)(b2 + rowb);
            #pragma unroll
            for (int jt = 0; jt < 3; ++jt) {
                f32x4 v = acc[i][jt];
                uint2v hv;
                hv[0] = pk2(fmaxf(v[0] + bv.x, 0.f), fmaxf(v[1] + bv.y, 0.f));
                hv[1] = pk2(fmaxf(v[2] + bv.z, 0.f), fmaxf(v[3] + bv.w, 0.f));
                *(uint2v*)&hL[jt * 16 + cl][rowb] = hv;
            }
        }
        __syncthreads();

        // ---- layer 3: r = W3 @ h2 + b3, 64 rows x 48 cols ----
        f32x4 acc3[3];
        #pragma unroll
        for (int jt = 0; jt < 3; ++jt) acc3[jt] = (f32x4){0.f, 0.f, 0.f, 0.f};

        for (int kt = 0; kt < 8; ++kt) {
            int k0 = kt * 32;
            bf16x8 a3 = *(const bf16x8*)(A3row + k0);
            #pragma unroll
            for (int jt = 0; jt < 3; ++jt) {
                bf16x8 bb = *(const bf16x8*)(&hL[jt * 16 + cl][k0 + q * 8]);
                acc3[jt] = __builtin_amdgcn_mfma_f32_16x16x32_bf16(a3, bb, acc3[jt], 0, 0, 0);
            }
        }

        // ---- epilogue: +b3, max over k (16 cols = cl), +x, store ----
        int rowb = w * 16 + q * 4;
        float4 b3v = *(const float4*)(b3 + rowb);
        #pragma unroll
        for (int jt = 0; jt < 3; ++jt) {
            int d = jt;
            f32x4 v = acc3[jt];
            v[0] += b3v.x;
            v[1] += b3v.y;
            v[2] += b3v.z;
            v[3] += b3v.w;
            #pragma unroll
            for (int off = 1; off < 16; off <<= 1) {
                v[0] = fmaxf(v[0], __shfl_xor(v[0], off));
                v[1] = fmaxf(v[1], __shfl_xor(v[1], off));
                v[2] = fmaxf(v[2], __shfl_xor(v[2], off));
                v[3] = fmaxf(v[3], __shfl_xor(v[3], off));
            }
            if (cl == 0) {
                #pragma unroll
                for (int rr = 0; rr < 4; ++rr) {
                    int addr = ((b * 64 + rowb + rr) * 3 + d) * 4096 + n;
                    out[addr] = v[rr] + x[addr];
                }
            }
        }
        __syncthreads();   // protect hL before next pass overwrites it
    }
}

extern "C" void kernel_launch(void* const* d_in, const int* in_sizes, int n_in,
                              void* d_out, int out_size, void* d_ws, size_t ws_size,
                              hipStream_t stream) {
    (void)in_sizes; (void)n_in; (void)out_size; (void)ws_size;
    const float* x  = (const float*)d_in[0];
    const float* W1 = (const float*)d_in[1];
    const float* b1 = (const float*)d_in[2];
    const float* W2 = (const float*)d_in[3];
    const float* b2 = (const float*)d_in[4];
    const float* W3 = (const float*)d_in[5];
    const float* b3 = (const float*)d_in[6];
    float* out = (float*)d_out;

    char* ws = (char*)d_ws;
    float* pc   = (float*)(ws + 0);          // 2,097,152 B  (B,C,N)
    float* sq   = (float*)(ws + 2097152);    //    32,768 B  (B,N)
    int*   idxw = (int*)  (ws + 2129920);    //   524,288 B  (B,N,K)
    u16*   Qbf  = (u16*)  (ws + 2654208);    // 4,194,304 B  (B,N,H) bf16
    u16*   Pbf  = (u16*)  (ws + 6848512);    // 12,582,912 B (B,D,N,H) bf16
    u16*   W2bf = (u16*)  (ws + 19431424);   //   131,072 B
    u16*   W3bf = (u16*)  (ws + 19562496);   //    32,768 B
    float* W1dT = (float*)(ws + 19595264);   //    65,536 B
    float* W1bT = (float*)(ws + 19660800);   //    65,536 B
    // KNN partials (16,777,216 B each). pd aliases the not-yet-written Qbf+Pbf
    // region exactly; pi lives after the weight buffers. q/p kernels run after
    // knn_merge, so the aliasing is safe. (prep runs first, inside mean_kernel,
    // and its buffers at 19.43-19.73 MB don't overlap pd or pi.)
    float* pd   = (float*)(ws + 2654208);    // ends 19,431,424
    int*   pi   = (int*)  (ws + 19726336);   // ends 36,503,552

    mean_kernel<<<2048, 256, 0, stream>>>(x, pc, W1, W2, W3, W2bf, W3bf, W1dT, W1bT);
    sq_kernel<<<32, 256, 0, stream>>>(pc, sq);
    knn_part_kernel<<<1024, 256, 0, stream>>>(pc, sq, pd, pi);
    knn_merge_kernel<<<2048, 256, 0, stream>>>(pd, pi, idxw);
    q_kernel<<<1024, 256, 0, stream>>>(pc, W1bT, Qbf);
    p_kernel<<<3072, 256, 0, stream>>>(x, W1dT, b1, Pbf);
    fused_mlp_kernel<<<4096, 256, 0, stream>>>(x, Pbf, Qbf, idxw, W2bf, W3bf, b2, b3, out);
}

// Round 9
// 360.040 us; speedup vs baseline: 1.5189x; 1.2972x over previous
//
#include <hip/hip_runtime.h>

typedef unsigned short u16;
typedef float f32x4 __attribute__((ext_vector_type(4)));
typedef short bf16x8 __attribute__((ext_vector_type(8)));
typedef u16 u16x4 __attribute__((ext_vector_type(4)));
typedef unsigned int uint2v __attribute__((ext_vector_type(2)));

// B=2, C=64, D=3, N=4096, K=16, E=128, H=256

static __device__ __forceinline__ u16 f2bf(float x) {
    union { float f; unsigned int u; } v; v.f = x;
    unsigned int u = v.u;
    unsigned int r = u + 0x7fffu + ((u >> 16) & 1u);   // RNE
    return (u16)(r >> 16);
}

static __device__ __forceinline__ float bf2f(u16 h) {
    union { unsigned int u; float f; } v; v.u = ((unsigned int)h) << 16;
    return v.f;
}

// packed RNE f32x2 -> bf16x2
static __device__ __forceinline__ unsigned int pk2(float a, float b) {
    return (unsigned int)f2bf(a) | ((unsigned int)f2bf(b) << 16);
}

// ---------------- mean over D (+ absorbed weight prep on blocks 0..255) ----
__global__ __launch_bounds__(256) void mean_kernel(const float* __restrict__ x,
                                                   float* __restrict__ pc,
                                                   const float* __restrict__ W1,
                                                   const float* __restrict__ W2,
                                                   const float* __restrict__ W3,
                                                   u16* __restrict__ W2bf,
                                                   u16* __restrict__ W3bf,
                                                   float* __restrict__ W1dT,
                                                   float* __restrict__ W1bT) {
    int t = blockIdx.x * 256 + threadIdx.x;            // over B*C*N = 524288
    int n = t & 4095;
    int bc = t >> 12;
    const float* xp = x + bc * 3 * 4096 + n;
    pc[t] = (xp[0] + xp[4096] + xp[8192]) / 3.0f;

    if (t < 65536) {                                   // prep (blocks 0..255)
        W2bf[t] = f2bf(W2[t]);
        if (t < 16384) {
            W3bf[t] = f2bf(W3[t]);
            int c = t >> 8, h = t & 255;
            float wa = W1[h * 128 + c];
            float wb = W1[h * 128 + 64 + c];
            W1dT[t] = wa - wb;                         // [c][h]
            W1bT[t] = wb;                              // [c][h]
        }
    }
}

// Branch-free sorted insert: exact fp32 compare, ~5 VALU/step, no divergence.
#define INSERT(dist, idxv) do { \
    float _v = (dist); int _vi = (idxv); \
    _Pragma("unroll") \
    for (int _s = 0; _s < 16; ++_s) { \
        bool _c = _v < bd[_s]; \
        float _nb = _c ? _v : bd[_s]; \
        float _nv = _c ? bd[_s] : _v; \
        int _nbi = _c ? _vi : bi[_s]; \
        int _nvi = _c ? bi[_s] : _vi; \
        bd[_s] = _nb; _v = _nv; bi[_s] = _nbi; _vi = _nvi; \
    } } while (0)

// ---------------- KNN phase 1: per-chunk top-16 (computes sq inline) --------
// grid = B(2) * QB(16) * CH(32) = 1024 blocks, 256 threads (1 query/thread),
// 128 candidates per chunk. sqt recomputed from staged tile; sqn from qv —
// identical c-order fp32 arithmetic everywhere -> identical distances.
__global__ __launch_bounds__(256, 3) void knn_part_kernel(const float* __restrict__ pc,
                                                          float* __restrict__ pd,
                                                          int* __restrict__ pi) {
    __shared__ float ptile[64][128];
    __shared__ float sqt[128];
    int tid = threadIdx.x;
    int bid = blockIdx.x;
    int ch = bid & 31, qb = (bid >> 5) & 15, b = bid >> 9;
    int n = qb * 256 + tid;
    int m0 = ch * 128;

    #pragma unroll
    for (int it = 0; it < 8; ++it) {
        int lin4 = it * 256 + tid;                     // 2048 float4s
        int c = lin4 >> 5, mm4 = (lin4 & 31) * 4;
        *(float4*)&ptile[c][mm4] =
            *(const float4*)&pc[(b * 64 + c) * 4096 + m0 + mm4];
    }
    __syncthreads();
    if (tid < 128) {                                   // candidate norms from tile
        float s = 0.f;
        #pragma unroll
        for (int c = 0; c < 64; ++c) {
            float v = ptile[c][tid];
            s = fmaf(v, v, s);
        }
        sqt[tid] = s;
    }

    float qv[64];
    float sqn = 0.f;
    #pragma unroll
    for (int c = 0; c < 64; ++c) {
        qv[c] = pc[(b * 64 + c) * 4096 + n];
        sqn = fmaf(qv[c], qv[c], sqn);
    }

    float bd[16]; int bi[16];
    #pragma unroll
    for (int s = 0; s < 16; ++s) { bd[s] = 3.4e38f; bi[s] = -1; }
    __syncthreads();

    for (int mb = 0; mb < 128; mb += 4) {
        float d0 = 0.f, d1 = 0.f, d2 = 0.f, d3 = 0.f;
        #pragma unroll
        for (int c = 0; c < 64; ++c) {
            float4 pv = *(const float4*)&ptile[c][mb];
            float qc = qv[c];
            d0 = fmaf(qc, pv.x, d0);
            d1 = fmaf(qc, pv.y, d1);
            d2 = fmaf(qc, pv.z, d2);
            d3 = fmaf(qc, pv.w, d3);
        }
        int m = m0 + mb;
        float e0 = (sqn - 2.f * d0) + sqt[mb + 0]; if (m + 0 == n) e0 = 3.4e38f;
        float e1 = (sqn - 2.f * d1) + sqt[mb + 1]; if (m + 1 == n) e1 = 3.4e38f;
        float e2 = (sqn - 2.f * d2) + sqt[mb + 2]; if (m + 2 == n) e2 = 3.4e38f;
        float e3 = (sqn - 2.f * d3) + sqt[mb + 3]; if (m + 3 == n) e3 = 3.4e38f;
        INSERT(e0, m + 0);
        INSERT(e1, m + 1);
        INSERT(e2, m + 2);
        INSERT(e3, m + 3);
    }
    int base = ((b * 4096 + n) * 32 + ch) * 16;
    #pragma unroll
    for (int s = 0; s < 16; ++s) { pd[base + s] = bd[s]; pi[base + s] = bi[s]; }
}

// ---------------- KNN phase 2: wave-per-query extract-min x16 ----------------
__global__ __launch_bounds__(256) void knn_merge_kernel(const float* __restrict__ pd,
                                                        const int* __restrict__ pi,
                                                        int* __restrict__ idxw) {
    int tid = threadIdx.x;
    int lane = tid & 63;
    int q = blockIdx.x * 4 + (tid >> 6);               // 2048 blocks, 4 queries each
    int base = q * 512;

    float d[8]; int ix[8];
    #pragma unroll
    for (int j = 0; j < 8; ++j) {
        d[j] = pd[base + lane + 64 * j];
        ix[j] = pi[base + lane + 64 * j];
    }

    for (int e = 0; e < 16; ++e) {
        float lmd = d[0]; int lmi = ix[0];
        #pragma unroll
        for (int j = 1; j < 8; ++j) {
            bool c = d[j] < lmd;
            lmd = c ? d[j] : lmd;
            lmi = c ? ix[j] : lmi;
        }
        float wm = lmd;
        #pragma unroll
        for (int off = 32; off; off >>= 1)
            wm = fminf(wm, __shfl_xor(wm, off));
        unsigned long long msk = __ballot(lmd == wm);
        int L = (int)__ffsll(msk) - 1;
        int wmi = __shfl(lmi, L);
        if (lane == 0) idxw[q * 16 + e] = wmi;
        if (lane == L) {
            #pragma unroll
            for (int j = 0; j < 8; ++j)
                if (ix[j] == wmi) d[j] = 3.4e38f;
        }
    }
}

// ---------------- fused q+p: bf16(W1b @ pc) and bf16((W1a-W1b) @ x + b1) -----
// grid 4096: blocks 0..1023 -> Qbf (8 m cols each); 1024..4095 -> Pbf.
__global__ __launch_bounds__(256) void qp_kernel(const float* __restrict__ pc,
                                                 const float* __restrict__ x,
                                                 const float* __restrict__ W1bT,
                                                 const float* __restrict__ W1dT,
                                                 const float* __restrict__ b1,
                                                 u16* __restrict__ Qbf,
                                                 u16* __restrict__ Pbf) {
    int h = threadIdx.x;
    int bid = blockIdx.x;
    if (bid < 1024) {
        int b = bid >> 9, m0 = (bid & 511) * 8;
        float a0 = 0.f, a1 = 0.f, a2 = 0.f, a3 = 0.f;
        float a4 = 0.f, a5 = 0.f, a6 = 0.f, a7 = 0.f;
        for (int c = 0; c < 64; ++c) {
            float w = W1bT[c * 256 + h];
            const float* pr = pc + (b * 64 + c) * 4096 + m0;
            float4 p0 = *(const float4*)pr;
            float4 p1 = *(const float4*)(pr + 4);
            a0 = fmaf(w, p0.x, a0); a1 = fmaf(w, p0.y, a1);
            a2 = fmaf(w, p0.z, a2); a3 = fmaf(w, p0.w, a3);
            a4 = fmaf(w, p1.x, a4); a5 = fmaf(w, p1.y, a5);
            a6 = fmaf(w, p1.z, a6); a7 = fmaf(w, p1.w, a7);
        }
        int ob = (b * 4096 + m0) * 256 + h;
        Qbf[ob] = f2bf(a0); Qbf[ob + 256] = f2bf(a1);
        Qbf[ob + 512] = f2bf(a2); Qbf[ob + 768] = f2bf(a3);
        Qbf[ob + 1024] = f2bf(a4); Qbf[ob + 1280] = f2bf(a5);
        Qbf[ob + 1536] = f2bf(a6); Qbf[ob + 1792] = f2bf(a7);
    } else {
        int pb = bid - 1024;                           // 3072
        int b = pb / 1536;
        int rem = pb % 1536;
        int d = rem >> 9;
        int n0 = (rem & 511) * 8;
        float bias = b1[h];
        float a0 = bias, a1 = bias, a2 = bias, a3 = bias;
        float a4 = bias, a5 = bias, a6 = bias, a7 = bias;
        for (int c = 0; c < 64; ++c) {
            float w = W1dT[c * 256 + h];
            const float* xr = x + ((b * 64 + c) * 3 + d) * 4096 + n0;
            float4 x0 = *(const float4*)xr;
            float4 x1 = *(const float4*)(xr + 4);
            a0 = fmaf(w, x0.x, a0); a1 = fmaf(w, x0.y, a1);
            a2 = fmaf(w, x0.z, a2); a3 = fmaf(w, x0.w, a3);
            a4 = fmaf(w, x1.x, a4); a5 = fmaf(w, x1.y, a5);
            a6 = fmaf(w, x1.z, a6); a7 = fmaf(w, x1.w, a7);
        }
        int ob = ((b * 3 + d) * 4096 + n0) * 256 + h;
        Pbf[ob] = f2bf(a0); Pbf[ob + 256] = f2bf(a1);
        Pbf[ob + 512] = f2bf(a2); Pbf[ob + 768] = f2bf(a3);
        Pbf[ob + 1024] = f2bf(a4); Pbf[ob + 1280] = f2bf(a5);
        Pbf[ob + 1536] = f2bf(a6); Pbf[ob + 1792] = f2bf(a7);
    }
}

// ---------------- fused layer2+layer3+maxK+residual (bf16 MFMA) ----------------
// R6 body (measured 155 us: VGPR 104, 3 blocks/CU) + XCD-contiguous n swizzle:
// blocks with bid&7 == xcd cover a contiguous 512-n span, so out-cache-lines
// (16 n) and the Q/P/idx gather working set stay within one XCD's L2.
__global__ __launch_bounds__(256) void fused_mlp_kernel(const float* __restrict__ x,
                                                        const u16* __restrict__ Pbf,
                                                        const u16* __restrict__ Qbf,
                                                        const int* __restrict__ idxw,
                                                        const u16* __restrict__ W2bf,
                                                        const u16* __restrict__ W3bf,
                                                        const float* __restrict__ b2,
                                                        const float* __restrict__ b3,
                                                        float* __restrict__ out) {
    __shared__ u16 hL[96][264];                        // stride 264: 16B-aligned, 2-way banks

    int tid = threadIdx.x;
    int bid = blockIdx.x;                              // 4096
    int b = bid >> 11;
    int rr = bid & 2047;
    int n0 = (((rr & 7) << 8) | (rr >> 3)) << 1;       // xcd-contiguous mapping

    int w = tid >> 6, lane = tid & 63;

    // ---- build h1 = relu(P + Q) into LDS (bf16) ----
    // wave w: point g = w&1, k-range kh..kh+7 (kh = (w>>1)*8); lane = h-chunk.
    {
        int g = w & 1, kh = (w >> 1) * 8;
        int n = n0 + g;
        u16x4 pv[3];
        #pragma unroll
        for (int d = 0; d < 3; ++d)
            pv[d] = *(const u16x4*)&Pbf[((b * 3 + d) * 4096 + n) * 256 + lane * 4];
        const int* idq = idxw + (b * 4096 + n) * 16 + kh;
        #pragma unroll
        for (int kk = 0; kk < 8; ++kk) {
            int m = idq[kk];                           // wave-uniform
            u16x4 qv = *(const u16x4*)&Qbf[(b * 4096 + m) * 256 + lane * 4];
            float q0 = bf2f(qv[0]), q1 = bf2f(qv[1]), q2 = bf2f(qv[2]), q3 = bf2f(qv[3]);
            #pragma unroll
            for (int d = 0; d < 3; ++d) {
                uint2v hv;
                hv[0] = pk2(fmaxf(bf2f(pv[d][0]) + q0, 0.f), fmaxf(bf2f(pv[d][1]) + q1, 0.f));
                hv[1] = pk2(fmaxf(bf2f(pv[d][2]) + q2, 0.f), fmaxf(bf2f(pv[d][3]) + q3, 0.f));
                *(uint2v*)&hL[g * 48 + d * 16 + kh + kk][lane * 4] = hv;
            }
        }
    }
    __syncthreads();

    int cl = lane & 15, q = lane >> 4;

    // ---- layer 2: h2 = relu(W2 @ h1 + b2), 256 rows x 96 cols ----
    f32x4 acc[4][6];
    #pragma unroll
    for (int i = 0; i < 4; ++i)
        #pragma unroll
        for (int jt = 0; jt < 6; ++jt)
            acc[i][jt] = (f32x4){0.f, 0.f, 0.f, 0.f};

    const u16* Arow = W2bf + (w * 64 + cl) * 256 + q * 8;
    for (int kt = 0; kt < 8; ++kt) {
        int k0 = kt * 32;
        bf16x8 a[4], bb[6];
        #pragma unroll
        for (int i = 0; i < 4; ++i)
            a[i] = *(const bf16x8*)(Arow + i * 4096 + k0);
        #pragma unroll
        for (int jt = 0; jt < 6; ++jt)
            bb[jt] = *(const bf16x8*)(&hL[jt * 16 + cl][k0 + q * 8]);
        #pragma unroll
        for (int i = 0; i < 4; ++i)
            #pragma unroll
            for (int jt = 0; jt < 6; ++jt)
                acc[i][jt] = __builtin_amdgcn_mfma_f32_16x16x32_bf16(a[i], bb[jt], acc[i][jt], 0, 0, 0);
    }
    __syncthreads();   // everyone done reading h1

    // write h2 (bf16) into the same LDS buffer; bias from L1
    #pragma unroll
    for (int i = 0; i < 4; ++i) {
        int rowb = w * 64 + i * 16 + q * 4;
        float4 bv = *(const float4*)(b2 + rowb);
        #pragma unroll
        for (int jt = 0; jt < 6; ++jt) {
            f32x4 v = acc[i][jt];
            uint2v hv;
            hv[0] = pk2(fmaxf(v[0] + bv.x, 0.f), fmaxf(v[1] + bv.y, 0.f));
            hv[1] = pk2(fmaxf(v[2] + bv.z, 0.f), fmaxf(v[3] + bv.w, 0.f));
            *(uint2v*)&hL[jt * 16 + cl][rowb] = hv;
        }
    }
    __syncthreads();

    // ---- layer 3: r = W3 @ h2 + b3, 64 rows x 96 cols; wave w -> rows w*16.. ----
    f32x4 acc3[6];
    #pragma unroll
    for (int jt = 0; jt < 6; ++jt) acc3[jt] = (f32x4){0.f, 0.f, 0.f, 0.f};

    const u16* A3row = W3bf + (w * 16 + cl) * 256 + q * 8;
    for (int kt = 0; kt < 8; ++kt) {
        int k0 = kt * 32;
        bf16x8 a3 = *(const bf16x8*)(A3row + k0);
        #pragma unroll
        for (int jt = 0; jt < 6; ++jt) {
            bf16x8 bb = *(const bf16x8*)(&hL[jt * 16 + cl][k0 + q * 8]);
            acc3[jt] = __builtin_amdgcn_mfma_f32_16x16x32_bf16(a3, bb, acc3[jt], 0, 0, 0);
        }
    }

    // ---- epilogue: +b3, max over k (16 cols of each tile = cl), +x, store ----
    int rowb = w * 16 + q * 4;
    float4 b3v = *(const float4*)(b3 + rowb);
    #pragma unroll
    for (int jt = 0; jt < 6; ++jt) {
        int g = jt / 3, d = jt % 3;
        int n = n0 + g;
        f32x4 v = acc3[jt];
        v[0] += b3v.x;
        v[1] += b3v.y;
        v[2] += b3v.z;
        v[3] += b3v.w;
        #pragma unroll
        for (int off = 1; off < 16; off <<= 1) {
            v[0] = fmaxf(v[0], __shfl_xor(v[0], off));
            v[1] = fmaxf(v[1], __shfl_xor(v[1], off));
            v[2] = fmaxf(v[2], __shfl_xor(v[2], off));
            v[3] = fmaxf(v[3], __shfl_xor(v[3], off));
        }
        if (cl == 0) {
            #pragma unroll
            for (int r = 0; r < 4; ++r) {
                int addr = ((b * 64 + rowb + r) * 3 + d) * 4096 + n;
                out[addr] = v[r] + x[addr];
            }
        }
    }
}

extern "C" void kernel_launch(void* const* d_in, const int* in_sizes, int n_in,
                              void* d_out, int out_size, void* d_ws, size_t ws_size,
                              hipStream_t stream) {
    (void)in_sizes; (void)n_in; (void)out_size; (void)ws_size;
    const float* x  = (const float*)d_in[0];
    const float* W1 = (const float*)d_in[1];
    const float* b1 = (const float*)d_in[2];
    const float* W2 = (const float*)d_in[3];
    const float* b2 = (const float*)d_in[4];
    const float* W3 = (const float*)d_in[5];
    const float* b3 = (const float*)d_in[6];
    float* out = (float*)d_out;

    char* ws = (char*)d_ws;
    float* pc   = (float*)(ws + 0);          // 2,097,152 B  (B,C,N)
    int*   idxw = (int*)  (ws + 2129920);    //   524,288 B  (B,N,K)
    u16*   Qbf  = (u16*)  (ws + 2654208);    // 4,194,304 B  (B,N,H) bf16
    u16*   Pbf  = (u16*)  (ws + 6848512);    // 12,582,912 B (B,D,N,H) bf16
    u16*   W2bf = (u16*)  (ws + 19431424);   //   131,072 B
    u16*   W3bf = (u16*)  (ws + 19562496);   //    32,768 B
    float* W1dT = (float*)(ws + 19595264);   //    65,536 B
    float* W1bT = (float*)(ws + 19660800);   //    65,536 B
    // KNN partials (16,777,216 B each). pd aliases the not-yet-written Qbf+Pbf
    // region exactly; pi lives after the weight buffers. qp_kernel runs after
    // knn_merge, so the aliasing is safe. (prep runs first, inside mean_kernel,
    // and its buffers at 19.43-19.73 MB don't overlap pd or pi.)
    float* pd   = (float*)(ws + 2654208);    // ends 19,431,424
    int*   pi   = (int*)  (ws + 19726336);   // ends 36,503,552

    mean_kernel<<<2048, 256, 0, stream>>>(x, pc, W1, W2, W3, W2bf, W3bf, W1dT, W1bT);
    knn_part_kernel<<<1024, 256, 0, stream>>>(pc, pd, pi);
    knn_merge_kernel<<<2048, 256, 0, stream>>>(pd, pi, idxw);
    qp_kernel<<<4096, 256, 0, stream>>>(pc, x, W1bT, W1dT, b1, Qbf, Pbf);
    fused_mlp_kernel<<<4096, 256, 0, stream>>>(x, Pbf, Qbf, idxw, W2bf, W3bf, b2, b3, out);
}

// Round 12
// 337.952 us; speedup vs baseline: 1.6182x; 1.0654x over previous
//
#include <hip/hip_runtime.h>

typedef unsigned short u16;
typedef float f32x4 __attribute__((ext_vector_type(4)));
typedef short bf16x8 __attribute__((ext_vector_type(8)));
typedef u16 u16x4 __attribute__((ext_vector_type(4)));
typedef unsigned int uint2v __attribute__((ext_vector_type(2)));

// B=2, C=64, D=3, N=4096, K=16, E=128, H=256

static __device__ __forceinline__ u16 f2bf(float x) {
    union { float f; unsigned int u; } v; v.f = x;
    unsigned int u = v.u;
    unsigned int r = u + 0x7fffu + ((u >> 16) & 1u);   // RNE
    return (u16)(r >> 16);
}

static __device__ __forceinline__ float bf2f(u16 h) {
    union { unsigned int u; float f; } v; v.u = ((unsigned int)h) << 16;
    return v.f;
}

// packed RNE f32x2 -> bf16x2
static __device__ __forceinline__ unsigned int pk2(float a, float b) {
    return (unsigned int)f2bf(a) | ((unsigned int)f2bf(b) << 16);
}

// ---------------- mean over D (+ absorbed weight prep on blocks 0..255) ----
__global__ __launch_bounds__(256) void mean_kernel(const float* __restrict__ x,
                                                   float* __restrict__ pc,
                                                   const float* __restrict__ W1,
                                                   const float* __restrict__ W2,
                                                   const float* __restrict__ W3,
                                                   u16* __restrict__ W2bf,
                                                   u16* __restrict__ W3bf,
                                                   float* __restrict__ W1dT,
                                                   float* __restrict__ W1bT) {
    int t = blockIdx.x * 256 + threadIdx.x;            // over B*C*N = 524288
    int n = t & 4095;
    int bc = t >> 12;
    const float* xp = x + bc * 3 * 4096 + n;
    pc[t] = (xp[0] + xp[4096] + xp[8192]) / 3.0f;

    if (t < 65536) {                                   // prep (blocks 0..255)
        W2bf[t] = f2bf(W2[t]);
        if (t < 16384) {
            W3bf[t] = f2bf(W3[t]);
            int c = t >> 8, h = t & 255;
            float wa = W1[h * 128 + c];
            float wb = W1[h * 128 + 64 + c];
            W1dT[t] = wa - wb;                         // [c][h]
            W1bT[t] = wb;                              // [c][h]
        }
    }
}

// Branch-free sorted insert: exact fp32 compare, ~5 VALU/step, no divergence.
#define INSERT(dist, idxv) do { \
    float _v = (dist); int _vi = (idxv); \
    _Pragma("unroll") \
    for (int _s = 0; _s < 16; ++_s) { \
        bool _c = _v < bd[_s]; \
        float _nb = _c ? _v : bd[_s]; \
        float _nv = _c ? bd[_s] : _v; \
        int _nbi = _c ? _vi : bi[_s]; \
        int _nvi = _c ? bi[_s] : _vi; \
        bd[_s] = _nb; _v = _nv; bi[_s] = _nbi; _vi = _nvi; \
    } } while (0)

// ---------------- KNN phase 1: per-chunk top-16 (computes sq inline) --------
__global__ __launch_bounds__(256, 3) void knn_part_kernel(const float* __restrict__ pc,
                                                          float* __restrict__ pd,
                                                          int* __restrict__ pi) {
    __shared__ float ptile[64][128];
    __shared__ float sqt[128];
    int tid = threadIdx.x;
    int bid = blockIdx.x;
    int ch = bid & 31, qb = (bid >> 5) & 15, b = bid >> 9;
    int n = qb * 256 + tid;
    int m0 = ch * 128;

    #pragma unroll
    for (int it = 0; it < 8; ++it) {
        int lin4 = it * 256 + tid;                     // 2048 float4s
        int c = lin4 >> 5, mm4 = (lin4 & 31) * 4;
        *(float4*)&ptile[c][mm4] =
            *(const float4*)&pc[(b * 64 + c) * 4096 + m0 + mm4];
    }
    __syncthreads();
    if (tid < 128) {                                   // candidate norms from tile
        float s = 0.f;
        #pragma unroll
        for (int c = 0; c < 64; ++c) {
            float v = ptile[c][tid];
            s = fmaf(v, v, s);
        }
        sqt[tid] = s;
    }

    float qv[64];
    float sqn = 0.f;
    #pragma unroll
    for (int c = 0; c < 64; ++c) {
        qv[c] = pc[(b * 64 + c) * 4096 + n];
        sqn = fmaf(qv[c], qv[c], sqn);
    }

    float bd[16]; int bi[16];
    #pragma unroll
    for (int s = 0; s < 16; ++s) { bd[s] = 3.4e38f; bi[s] = -1; }
    __syncthreads();

    for (int mb = 0; mb < 128; mb += 4) {
        float d0 = 0.f, d1 = 0.f, d2 = 0.f, d3 = 0.f;
        #pragma unroll
        for (int c = 0; c < 64; ++c) {
            float4 pv = *(const float4*)&ptile[c][mb];
            float qc = qv[c];
            d0 = fmaf(qc, pv.x, d0);
            d1 = fmaf(qc, pv.y, d1);
            d2 = fmaf(qc, pv.z, d2);
            d3 = fmaf(qc, pv.w, d3);
        }
        int m = m0 + mb;
        float e0 = (sqn - 2.f * d0) + sqt[mb + 0]; if (m + 0 == n) e0 = 3.4e38f;
        float e1 = (sqn - 2.f * d1) + sqt[mb + 1]; if (m + 1 == n) e1 = 3.4e38f;
        float e2 = (sqn - 2.f * d2) + sqt[mb + 2]; if (m + 2 == n) e2 = 3.4e38f;
        float e3 = (sqn - 2.f * d3) + sqt[mb + 3]; if (m + 3 == n) e3 = 3.4e38f;
        INSERT(e0, m + 0);
        INSERT(e1, m + 1);
        INSERT(e2, m + 2);
        INSERT(e3, m + 3);
    }
    int base = ((b * 4096 + n) * 32 + ch) * 16;
    #pragma unroll
    for (int s = 0; s < 16; ++s) { pd[base + s] = bd[s]; pi[base + s] = bi[s]; }
}

// ---------------- KNN phase 2: wave-per-query extract-min x16 ----------------
__global__ __launch_bounds__(256) void knn_merge_kernel(const float* __restrict__ pd,
                                                        const int* __restrict__ pi,
                                                        int* __restrict__ idxw) {
    int tid = threadIdx.x;
    int lane = tid & 63;
    int q = blockIdx.x * 4 + (tid >> 6);               // 2048 blocks, 4 queries each
    int base = q * 512;

    float d[8]; int ix[8];
    #pragma unroll
    for (int j = 0; j < 8; ++j) {
        d[j] = pd[base + lane + 64 * j];
        ix[j] = pi[base + lane + 64 * j];
    }

    for (int e = 0; e < 16; ++e) {
        float lmd = d[0]; int lmi = ix[0];
        #pragma unroll
        for (int j = 1; j < 8; ++j) {
            bool c = d[j] < lmd;
            lmd = c ? d[j] : lmd;
            lmi = c ? ix[j] : lmi;
        }
        float wm = lmd;
        #pragma unroll
        for (int off = 32; off; off >>= 1)
            wm = fminf(wm, __shfl_xor(wm, off));
        unsigned long long msk = __ballot(lmd == wm);
        int L = (int)__ffsll(msk) - 1;
        int wmi = __shfl(lmi, L);
        if (lane == 0) idxw[q * 16 + e] = wmi;
        if (lane == L) {
            #pragma unroll
            for (int j = 0; j < 8; ++j)
                if (ix[j] == wmi) d[j] = 3.4e38f;
        }
    }
}

// ---------------- fused q+p: bf16(W1b @ pc) and bf16((W1a-W1b) @ x + b1) -----
// grid 4096: blocks 0..1023 -> Qbf (8 m cols each); 1024..4095 -> Pbf.
__global__ __launch_bounds__(256) void qp_kernel(const float* __restrict__ pc,
                                                 const float* __restrict__ x,
                                                 const float* __restrict__ W1bT,
                                                 const float* __restrict__ W1dT,
                                                 const float* __restrict__ b1,
                                                 u16* __restrict__ Qbf,
                                                 u16* __restrict__ Pbf) {
    int h = threadIdx.x;
    int bid = blockIdx.x;
    if (bid < 1024) {
        int b = bid >> 9, m0 = (bid & 511) * 8;
        float a0 = 0.f, a1 = 0.f, a2 = 0.f, a3 = 0.f;
        float a4 = 0.f, a5 = 0.f, a6 = 0.f, a7 = 0.f;
        for (int c = 0; c < 64; ++c) {
            float w = W1bT[c * 256 + h];
            const float* pr = pc + (b * 64 + c) * 4096 + m0;
            float4 p0 = *(const float4*)pr;
            float4 p1 = *(const float4*)(pr + 4);
            a0 = fmaf(w, p0.x, a0); a1 = fmaf(w, p0.y, a1);
            a2 = fmaf(w, p0.z, a2); a3 = fmaf(w, p0.w, a3);
            a4 = fmaf(w, p1.x, a4); a5 = fmaf(w, p1.y, a5);
            a6 = fmaf(w, p1.z, a6); a7 = fmaf(w, p1.w, a7);
        }
        int ob = (b * 4096 + m0) * 256 + h;
        Qbf[ob] = f2bf(a0); Qbf[ob + 256] = f2bf(a1);
        Qbf[ob + 512] = f2bf(a2); Qbf[ob + 768] = f2bf(a3);
        Qbf[ob + 1024] = f2bf(a4); Qbf[ob + 1280] = f2bf(a5);
        Qbf[ob + 1536] = f2bf(a6); Qbf[ob + 1792] = f2bf(a7);
    } else {
        int pb = bid - 1024;                           // 3072
        int b = pb / 1536;
        int rem = pb % 1536;
        int d = rem >> 9;
        int n0 = (rem & 511) * 8;
        float bias = b1[h];
        float a0 = bias, a1 = bias, a2 = bias, a3 = bias;
        float a4 = bias, a5 = bias, a6 = bias, a7 = bias;
        for (int c = 0; c < 64; ++c) {
            float w = W1dT[c * 256 + h];
            const float* xr = x + ((b * 64 + c) * 3 + d) * 4096 + n0;
            float4 x0 = *(const float4*)xr;
            float4 x1 = *(const float4*)(xr + 4);
            a0 = fmaf(w, x0.x, a0); a1 = fmaf(w, x0.y, a1);
            a2 = fmaf(w, x0.z, a2); a3 = fmaf(w, x0.w, a3);
            a4 = fmaf(w, x1.x, a4); a5 = fmaf(w, x1.y, a5);
            a6 = fmaf(w, x1.z, a6); a7 = fmaf(w, x1.w, a7);
        }
        int ob = ((b * 3 + d) * 4096 + n0) * 256 + h;
        Pbf[ob] = f2bf(a0); Pbf[ob + 256] = f2bf(a1);
        Pbf[ob + 512] = f2bf(a2); Pbf[ob + 768] = f2bf(a3);
        Pbf[ob + 1024] = f2bf(a4); Pbf[ob + 1280] = f2bf(a5);
        Pbf[ob + 1536] = f2bf(a6); Pbf[ob + 1792] = f2bf(a7);
    }
}

// ---------------- fused layer2+layer3+maxK+residual (bf16 MFMA) ----------------
// 8-wave (512-thread) blocks, 2 points/block, 96x264 hL (50.7 KB), grid 4096
// (R11 bug: grid was 2048 -> half of B*N=8192 points never written).
// Work split: h1 build 4 k/wave; layer2 rows 32/wave (acc[2][6]); layer3 split
// rows (w&3) x col-half (w>>2). Same numerics as R9; more waves/CU for latency
// hiding. XCD-contiguous n swizzle (256-point span per XCD).
__global__ __launch_bounds__(512) void fused_mlp_kernel(const float* __restrict__ x,
                                                        const u16* __restrict__ Pbf,
                                                        const u16* __restrict__ Qbf,
                                                        const int* __restrict__ idxw,
                                                        const u16* __restrict__ W2bf,
                                                        const u16* __restrict__ W3bf,
                                                        const float* __restrict__ b2,
                                                        const float* __restrict__ b3,
                                                        float* __restrict__ out) {
    __shared__ u16 hL[96][264];                        // stride 264: 16B-aligned, 2-way banks

    int tid = threadIdx.x;
    int bid = blockIdx.x;                              // 4096
    int b = bid >> 11;
    int rr = bid & 2047;
    int n0 = (((rr & 7) << 8) | (rr >> 3)) << 1;       // xcd-contiguous mapping

    int w = tid >> 6, lane = tid & 63;
    int cl = lane & 15, q = lane >> 4;

    // ---- build h1 = relu(P + Q) into LDS (bf16) ----
    // wave w: point g = w&1, k-range kh..kh+3 (kh = (w>>1)*4); lane = h-chunk.
    {
        int g = w & 1, kh = (w >> 1) * 4;
        int n = n0 + g;
        u16x4 pv[3];
        #pragma unroll
        for (int d = 0; d < 3; ++d)
            pv[d] = *(const u16x4*)&Pbf[((b * 3 + d) * 4096 + n) * 256 + lane * 4];
        const int* idq = idxw + (b * 4096 + n) * 16 + kh;
        #pragma unroll
        for (int kk = 0; kk < 4; ++kk) {
            int m = idq[kk];                           // wave-uniform
            u16x4 qv = *(const u16x4*)&Qbf[(b * 4096 + m) * 256 + lane * 4];
            float q0 = bf2f(qv[0]), q1 = bf2f(qv[1]), q2 = bf2f(qv[2]), q3 = bf2f(qv[3]);
            #pragma unroll
            for (int d = 0; d < 3; ++d) {
                uint2v hv;
                hv[0] = pk2(fmaxf(bf2f(pv[d][0]) + q0, 0.f), fmaxf(bf2f(pv[d][1]) + q1, 0.f));
                hv[1] = pk2(fmaxf(bf2f(pv[d][2]) + q2, 0.f), fmaxf(bf2f(pv[d][3]) + q3, 0.f));
                *(uint2v*)&hL[g * 48 + d * 16 + kh + kk][lane * 4] = hv;
            }
        }
    }
    __syncthreads();

    // ---- layer 2: h2 = relu(W2 @ h1 + b2), 256 rows x 96 cols ----
    // wave w -> rows w*32 .. w*32+31 (2 row-tiles)
    f32x4 acc[2][6];
    #pragma unroll
    for (int i = 0; i < 2; ++i)
        #pragma unroll
        for (int jt = 0; jt < 6; ++jt)
            acc[i][jt] = (f32x4){0.f, 0.f, 0.f, 0.f};

    const u16* Arow = W2bf + (w * 32 + cl) * 256 + q * 8;
    for (int kt = 0; kt < 8; ++kt) {
        int k0 = kt * 32;
        bf16x8 a[2], bb[6];
        #pragma unroll
        for (int i = 0; i < 2; ++i)
            a[i] = *(const bf16x8*)(Arow + i * 4096 + k0);
        #pragma unroll
        for (int jt = 0; jt < 6; ++jt)
            bb[jt] = *(const bf16x8*)(&hL[jt * 16 + cl][k0 + q * 8]);
        #pragma unroll
        for (int i = 0; i < 2; ++i)
            #pragma unroll
            for (int jt = 0; jt < 6; ++jt)
                acc[i][jt] = __builtin_amdgcn_mfma_f32_16x16x32_bf16(a[i], bb[jt], acc[i][jt], 0, 0, 0);
    }
    __syncthreads();   // everyone done reading h1

    // write h2 (bf16) into the same LDS buffer; bias from L1
    #pragma unroll
    for (int i = 0; i < 2; ++i) {
        int rowb = w * 32 + i * 16 + q * 4;
        float4 bv = *(const float4*)(b2 + rowb);
        #pragma unroll
        for (int jt = 0; jt < 6; ++jt) {
            f32x4 v = acc[i][jt];
            uint2v hv;
            hv[0] = pk2(fmaxf(v[0] + bv.x, 0.f), fmaxf(v[1] + bv.y, 0.f));
            hv[1] = pk2(fmaxf(v[2] + bv.z, 0.f), fmaxf(v[3] + bv.w, 0.f));
            *(uint2v*)&hL[jt * 16 + cl][rowb] = hv;
        }
    }
    __syncthreads();

    // ---- layer 3: r = W3 @ h2 + b3, 64 rows x 96 cols ----
    // wave w -> rows (w&3)*16.., col-half jt0 = (w>>2)*3 (3 of 6 tiles)
    int rw = (w & 3) * 16, jt0 = (w >> 2) * 3;
    f32x4 acc3[3];
    #pragma unroll
    for (int jt = 0; jt < 3; ++jt) acc3[jt] = (f32x4){0.f, 0.f, 0.f, 0.f};

    const u16* A3row = W3bf + (rw + cl) * 256 + q * 8;
    for (int kt = 0; kt < 8; ++kt) {
        int k0 = kt * 32;
        bf16x8 a3 = *(const bf16x8*)(A3row + k0);
        #pragma unroll
        for (int jt = 0; jt < 3; ++jt) {
            bf16x8 bb = *(const bf16x8*)(&hL[(jt0 + jt) * 16 + cl][k0 + q * 8]);
            acc3[jt] = __builtin_amdgcn_mfma_f32_16x16x32_bf16(a3, bb, acc3[jt], 0, 0, 0);
        }
    }

    // ---- epilogue: +b3, max over k (16 cols of each tile = cl), +x, store ----
    int rowb = rw + q * 4;
    float4 b3v = *(const float4*)(b3 + rowb);
    #pragma unroll
    for (int jt = 0; jt < 3; ++jt) {
        int jj = jt0 + jt;
        int g = jj / 3, d = jj % 3;
        int n = n0 + g;
        f32x4 v = acc3[jt];
        v[0] += b3v.x;
        v[1] += b3v.y;
        v[2] += b3v.z;
        v[3] += b3v.w;
        #pragma unroll
        for (int off = 1; off < 16; off <<= 1) {
            v[0] = fmaxf(v[0], __shfl_xor(v[0], off));
            v[1] = fmaxf(v[1], __shfl_xor(v[1], off));
            v[2] = fmaxf(v[2], __shfl_xor(v[2], off));
            v[3] = fmaxf(v[3], __shfl_xor(v[3], off));
        }
        if (cl == 0) {
            #pragma unroll
            for (int r = 0; r < 4; ++r) {
                int addr = ((b * 64 + rowb + r) * 3 + d) * 4096 + n;
                out[addr] = v[r] + x[addr];
            }
        }
    }
}

extern "C" void kernel_launch(void* const* d_in, const int* in_sizes, int n_in,
                              void* d_out, int out_size, void* d_ws, size_t ws_size,
                              hipStream_t stream) {
    (void)in_sizes; (void)n_in; (void)out_size; (void)ws_size;
    const float* x  = (const float*)d_in[0];
    const float* W1 = (const float*)d_in[1];
    const float* b1 = (const float*)d_in[2];
    const float* W2 = (const float*)d_in[3];
    const float* b2 = (const float*)d_in[4];
    const float* W3 = (const float*)d_in[5];
    const float* b3 = (const float*)d_in[6];
    float* out = (float*)d_out;

    char* ws = (char*)d_ws;
    float* pc   = (float*)(ws + 0);          // 2,097,152 B  (B,C,N)
    int*   idxw = (int*)  (ws + 2129920);    //   524,288 B  (B,N,K)
    u16*   Qbf  = (u16*)  (ws + 2654208);    // 4,194,304 B  (B,N,H) bf16
    u16*   Pbf  = (u16*)  (ws + 6848512);    // 12,582,912 B (B,D,N,H) bf16
    u16*   W2bf = (u16*)  (ws + 19431424);   //   131,072 B
    u16*   W3bf = (u16*)  (ws + 19562496);   //    32,768 B
    float* W1dT = (float*)(ws + 19595264);   //    65,536 B
    float* W1bT = (float*)(ws + 19660800);   //    65,536 B
    // KNN partials (16,777,216 B each). pd aliases the not-yet-written Qbf+Pbf
    // region exactly; pi lives after the weight buffers (ends 36,503,552 —
    // PROVEN ws limit). knn_merge completes before qp_kernel writes Qbf/Pbf.
    float* pd   = (float*)(ws + 2654208);    // ends 19,431,424
    int*   pi   = (int*)  (ws + 19726336);   // ends 36,503,552

    mean_kernel<<<2048, 256, 0, stream>>>(x, pc, W1, W2, W3, W2bf, W3bf, W1dT, W1bT);
    knn_part_kernel<<<1024, 256, 0, stream>>>(pc, pd, pi);
    knn_merge_kernel<<<2048, 256, 0, stream>>>(pd, pi, idxw);
    qp_kernel<<<4096, 256, 0, stream>>>(pc, x, W1bT, W1dT, b1, Qbf, Pbf);
    fused_mlp_kernel<<<4096, 512, 0, stream>>>(x, Pbf, Qbf, idxw, W2bf, W3bf, b2, b3, out);
}